// Round 13
// baseline (282.470 us; speedup 1.0000x reference)
//
#include <hip/hip_runtime.h>
#include <stdint.h>

#define N_TOK 4096
#define DIM   1024          // K elements = K bytes in fp8
#define NCLS  32000
#define IGNIDX (-100)
#define BM 128
#define BN 128
#define BKB 128             // fp8 K-bytes per tile
#define NTN (NCLS / BN)     // 250 col-tiles
#define NTM (N_TOK / BM)    // 32 row-tiles
#define KT  (DIM / BKB)     // 8 K-tiles

typedef float   f32x4 __attribute__((ext_vector_type(4)));
typedef int     i32x4 __attribute__((ext_vector_type(4)));
typedef int     i32x8 __attribute__((ext_vector_type(8)));
typedef uint8_t u8;

#define VMCNT0 asm volatile("s_waitcnt vmcnt(0)" ::: "memory")
#define FENCE asm volatile("" ::: "memory")
#define BAR __builtin_amdgcn_s_barrier()

#define SCALE_ONE 0x7F7F7F7F   // e8m0 2^0 in every byte

// ---- fp32 -> fp8 e4m3 bulk convert (8 elems/thread) ----
__global__ void cvt_fp8(const float4* __restrict__ in, uint2* __restrict__ out, int n8) {
  int i = blockIdx.x * 256 + threadIdx.x;
  if (i >= n8) return;
  float4 a = in[2 * i], b = in[2 * i + 1];
  int lo = 0, hi = 0;
  lo = __builtin_amdgcn_cvt_pk_fp8_f32(a.x, a.y, lo, false);
  lo = __builtin_amdgcn_cvt_pk_fp8_f32(a.z, a.w, lo, true);
  hi = __builtin_amdgcn_cvt_pk_fp8_f32(b.x, b.y, hi, false);
  hi = __builtin_amdgcn_cvt_pk_fp8_f32(b.z, b.w, hi, true);
  out[i] = make_uint2((unsigned)lo, (unsigned)hi);
}

// ---- effective targets, ignore flags, divisor ----
__global__ void prep_targ(const int* __restrict__ targ, int* __restrict__ teff,
                          int* __restrict__ ign, float* __restrict__ divisor) {
  __shared__ int cnt[16];
  int local = 0;
  for (int i = threadIdx.x; i < N_TOK; i += 1024) {
    int t = targ[i];
    if (t != IGNIDX) local++;
    int pos = i & (N_TOK / 4 - 1);
    int te;
    if (pos < N_TOK / 4 - 1)      te = targ[i + 1];
    else if (i == N_TOK - 1)      te = IGNIDX;
    else                          te = targ[i + 2];
    ign[i] = (te == IGNIDX) ? 1 : 0;
    te = te < 0 ? 0 : (te > NCLS - 1 ? NCLS - 1 : te);
    teff[i] = te;
  }
#pragma unroll
  for (int d = 1; d < 64; d <<= 1) local += __shfl_xor(local, d);
  if ((threadIdx.x & 63) == 0) cnt[threadIdx.x >> 6] = local;
  __syncthreads();
  if (threadIdx.x == 0) {
    int t = 0;
    for (int i = 0; i < 16; i++) t += cnt[i];
    divisor[0] = (float)t;
  }
}

// LDS flat layout (bytes): A0 @0, A1 @16384, B0 @32768, B1 @49152 = 64 KiB.
// Staged 16B slot s of row r holds logical K-granule s ^ (r&7) (involution).

// direct global->LDS, 16B/lane, linear LDS dest (wave-uniform base)
#define STG(GSRC, LOFF) __builtin_amdgcn_global_load_lds(                  \
    (const __attribute__((address_space(1))) void*)(GSRC),                 \
    (__attribute__((address_space(3))) void*)&lds[LOFF], 16, 0, 0)

// one 16x16x128 fragment = 2 x ds_read_b128 (even/odd granule), 32-bit addrs
#define FRAG(DST, EB, OB, IMM)                                             \
  { i32x4 _a = *(const i32x4*)&lds[(EB) + (IMM)];                          \
    i32x4 _b = *(const i32x4*)&lds[(OB) + (IMM)];                          \
    DST[0] = _a[0]; DST[1] = _a[1]; DST[2] = _a[2]; DST[3] = _a[3];        \
    DST[4] = _b[0]; DST[5] = _b[1]; DST[6] = _b[2]; DST[7] = _b[3]; }

// ---- fused 128x128 MX-fp8 GEMM + per-tile sum(exp) partials ----
// Round-13: 2 independent blocks/CU (64 KiB LDS each). The two blocks'
// read/MFMA phases are unsynchronized -> LDS pipe and MFMA pipe of the CU
// run concurrently (m114 mechanism), converting the per-CU phase SUM
// (round-12's 7700cyc/K-tile at 1 block/CU lockstep) toward MAX.
// 4 waves (2x2), 64x64 per wave, acc = 64 VGPR (register cliff cleared).
__launch_bounds__(256, 2)
__global__ void gemm_lse(const u8* __restrict__ Xf8, const u8* __restrict__ Wf8,
                         const int* __restrict__ teff, float* __restrict__ gt,
                         float* __restrict__ partial) {
  __shared__ __align__(16) u8 lds[65536];

  const int tid = threadIdx.x;
  const int w = tid >> 6, l = tid & 63;
  const int wr = w >> 1, wc = w & 1;          // 2 x 2 wave grid
  const int hi = l >> 4, lo = l & 15;
  const int q = l & 7;

  // XCD-chunked bijective swizzle (8000 % 8 == 0)
  const int bid = blockIdx.x;
  const int wg = (bid & 7) * (NTM * NTN / 8) + (bid >> 3);
  const int bx = wg & (NTM - 1), by = wg >> 5;     // 32 row-tiles, 250 col-tiles
  const int rowBase = bx * BM, colBase = by * BN;

  // uniform global bases (SGPR) + invariant per-lane 32-bit offset
  const u8* pA = Xf8 + (size_t)rowBase * DIM;
  const u8* pB = Wf8 + (size_t)colBase * DIM;
  const int lr = l >> 3, lg = (l & 7) ^ lr;
  const int voff = (w * 8 + lr) * DIM + lg * 16;   // same row-mapping for A and B
  // wave-uniform LDS staging sub-base (within a region)
  const int ldsW = w * 1024;

  // per-lane fragment-read bases (32-bit LDS byte offsets)
  const int slotE = (((hi * 2) ^ q)) << 4;
  const int aE = (wr * 64 + lo) * BKB + slotE;
  const int aO = aE ^ 16;
  const int bE = 32768 + (wc * 64 + lo) * BKB + slotE;
  const int bO = bE ^ 16;

  f32x4 acc[4][4] = {};

  // ---- prologue: stage tile 0 -> buf0 (8 calls: 4 A-regions + 4 B-regions) ----
  STG(pA + voff, ldsW);                    STG(pA + 32768 + voff, ldsW + 4096);
  STG(pA + 65536 + voff, ldsW + 8192);     STG(pA + 98304 + voff, ldsW + 12288);
  STG(pB + voff, 32768 + ldsW);            STG(pB + 32768 + voff, 32768 + ldsW + 4096);
  STG(pB + 65536 + voff, 32768 + ldsW + 8192); STG(pB + 98304 + voff, 32768 + ldsW + 12288);
  VMCNT0; FENCE; BAR;

  i32x8 aF[4], bF[4];

#pragma unroll 1
  for (int t = 0; t < KT; t++) {
    const int bs  = (t & 1) << 14;          // current buffer byte offset (A and B)
    const int bn_ = bs ^ 16384;             // other buffer
    const int aEc = aE + bs, aOc = aO + bs;
    const int bEc = bE + bs, bOc = bO + bs;
    const int k1 = ((t + 1) & 7) * BKB;     // uniform (SALU)

    // stage tile t+1 (all regions) -> other buffer; hides under MFMAs
    STG(pA + k1 + voff, ldsW + bn_);
    STG(pA + (k1 + 32768) + voff, ldsW + 4096 + bn_);
    STG(pA + (k1 + 65536) + voff, ldsW + 8192 + bn_);
    STG(pA + (k1 + 98304) + voff, ldsW + 12288 + bn_);
    STG(pB + k1 + voff, 32768 + ldsW + bn_);
    STG(pB + (k1 + 32768) + voff, 32768 + ldsW + 4096 + bn_);
    STG(pB + (k1 + 65536) + voff, 32768 + ldsW + 8192 + bn_);
    STG(pB + (k1 + 98304) + voff, 32768 + ldsW + 12288 + bn_);

    // 16 reads -> 16 MFMA
    FRAG(aF[0], aEc, aOc, 0)
    FRAG(aF[1], aEc, aOc, 2048)
    FRAG(aF[2], aEc, aOc, 4096)
    FRAG(aF[3], aEc, aOc, 6144)
    FRAG(bF[0], bEc, bOc, 0)
    FRAG(bF[1], bEc, bOc, 2048)
    FRAG(bF[2], bEc, bOc, 4096)
    FRAG(bF[3], bEc, bOc, 6144)

    __builtin_amdgcn_s_setprio(1);
#pragma unroll
    for (int mm = 0; mm < 4; mm++)
#pragma unroll
      for (int nn = 0; nn < 4; nn++)
        acc[mm][nn] = __builtin_amdgcn_mfma_scale_f32_16x16x128_f8f6f4(
            aF[mm], bF[nn], acc[mm][nn], 0, 0, 0, SCALE_ONE, 0, SCALE_ONE);
    __builtin_amdgcn_s_setprio(0);

    VMCNT0; FENCE; BAR;
  }

  // ---- epilogue: per-row sum(exp) over this 128-col tile + gt extraction ----
  float* red = (float*)lds;   // safe: all stages drained (VMCNT0 above)
#pragma unroll
  for (int m = 0; m < 4; m++) {
#pragma unroll
    for (int j = 0; j < 4; j++) {
      const int rloc = wr * 64 + m * 16 + hi * 4 + j;
      const int gr = rowBase + rloc;
      const int te = teff[gr];
      float s = 0.f;
#pragma unroll
      for (int n = 0; n < 4; n++) {
        float v = acc[m][n][j];
        const int gc = colBase + wc * 64 + n * 16 + lo;
        if (te == gc) gt[gr] = v;
        s += __expf(v);
      }
#pragma unroll
      for (int d = 1; d < 16; d <<= 1) s += __shfl_xor(s, d);
      if (lo == 0) red[wc * 128 + rloc] = s;
    }
  }
  __syncthreads();
  if (tid < 128) {
    float S = red[tid] + red[128 + tid];
    partial[(size_t)(rowBase + tid) * NTN + by] = S;
  }
}

// ---- combine 250 tile partials per row -> per-token loss ----
__global__ void reduce_lse(const float* __restrict__ partial, const float* __restrict__ gt,
                           const int* __restrict__ ign, const float* __restrict__ divisor,
                           float* __restrict__ pertok) {
  int r = blockIdx.x * 4 + (threadIdx.x >> 6);
  int l = threadIdx.x & 63;
  float S = 0.f;
  for (int p = l; p < NTN; p += 64) S += partial[(size_t)r * NTN + p];
#pragma unroll
  for (int d = 1; d < 64; d <<= 1) S += __shfl_xor(S, d);
  if (l == 0) {
    float lse = __logf(S);
    pertok[r] = ign[r] ? 0.f : (lse - gt[r]) / divisor[0];
  }
}

// ---- deterministic final sum ----
__global__ void final_sum(const float* __restrict__ pertok, float* __restrict__ out) {
  __shared__ float red[16];
  float s = 0.f;
  for (int i = threadIdx.x; i < N_TOK; i += 1024) s += pertok[i];
#pragma unroll
  for (int d = 1; d < 64; d <<= 1) s += __shfl_xor(s, d);
  if ((threadIdx.x & 63) == 0) red[threadIdx.x >> 6] = s;
  __syncthreads();
  if (threadIdx.x == 0) {
    float t = 0.f;
    for (int i = 0; i < 16; i++) t += red[i];
    out[0] = t;
  }
}

extern "C" void kernel_launch(void* const* d_in, const int* in_sizes, int n_in,
                              void* d_out, int out_size, void* d_ws, size_t ws_size,
                              hipStream_t stream) {
  const float* x = (const float*)d_in[0];       // [4096,1024] f32
  const float* w = (const float*)d_in[1];       // [32000,1024] f32
  const int* targ = (const int*)d_in[2];        // [4096] int
  float* out = (float*)d_out;

  char* ws = (char*)d_ws;
  u8*    Xf8     = (u8*)(ws);                      // 4,194,304 B
  u8*    Wf8     = (u8*)(ws + 4194304);            // 32,768,000 B
  float* partial = (float*)(ws + 36962304);        // 4,096,000 B (4096 x 250)
  float* gt      = (float*)(ws + 41058304);        // 16,384 B
  int*   teff    = (int*)(ws + 41074688);          // 16,384 B
  int*   ign     = (int*)(ws + 41091072);          // 16,384 B
  float* divisor = (float*)(ws + 41107456);        // 256 B
  float* pertok  = (float*)(ws + 41107712);        // 16,384 B

  {
    int n8 = N_TOK * DIM / 8;                      // 524288
    cvt_fp8<<<(n8 + 255) / 256, 256, 0, stream>>>((const float4*)x, (uint2*)Xf8, n8);
  }
  {
    int n8 = NCLS * DIM / 8;                       // 4,096,000
    cvt_fp8<<<(n8 + 255) / 256, 256, 0, stream>>>((const float4*)w, (uint2*)Wf8, n8);
  }
  prep_targ<<<1, 1024, 0, stream>>>(targ, teff, ign, divisor);

  gemm_lse<<<NTM * NTN, 256, 0, stream>>>(Xf8, Wf8, teff, gt, partial);  // 8000 blocks

  reduce_lse<<<N_TOK / 4, 256, 0, stream>>>(partial, gt, ign, divisor, pertok);
  final_sum<<<1, 1024, 0, stream>>>(pertok, out);
}

// Round 14
// 229.535 us; speedup vs baseline: 1.2306x; 1.2306x over previous
//
#include <hip/hip_runtime.h>
#include <stdint.h>

#define N_TOK 4096
#define DIM   1024          // K elements = K bytes in fp8
#define NCLS  32000
#define IGNIDX (-100)
#define BM 256
#define BN 256
#define BKB 128             // fp8 K-bytes per tile
#define NTN (NCLS / BN)     // 125 col-tiles
#define NTM (N_TOK / BM)    // 16 row-tiles
#define KT  (DIM / BKB)     // 8 K-tiles

typedef float   f32x4 __attribute__((ext_vector_type(4)));
typedef int     i32x4 __attribute__((ext_vector_type(4)));
typedef int     i32x8 __attribute__((ext_vector_type(8)));
typedef uint8_t u8;

#define VMCNT0 asm volatile("s_waitcnt vmcnt(0)" ::: "memory")
#define FENCE asm volatile("" ::: "memory")
#define BAR __builtin_amdgcn_s_barrier()

#define SCALE_ONE 0x7F7F7F7F   // e8m0 2^0 in every byte

// ---- fp32 -> fp8 e4m3 bulk convert (8 elems/thread) ----
__global__ void cvt_fp8(const float4* __restrict__ in, uint2* __restrict__ out, int n8) {
  int i = blockIdx.x * 256 + threadIdx.x;
  if (i >= n8) return;
  float4 a = in[2 * i], b = in[2 * i + 1];
  int lo = 0, hi = 0;
  lo = __builtin_amdgcn_cvt_pk_fp8_f32(a.x, a.y, lo, false);
  lo = __builtin_amdgcn_cvt_pk_fp8_f32(a.z, a.w, lo, true);
  hi = __builtin_amdgcn_cvt_pk_fp8_f32(b.x, b.y, hi, false);
  hi = __builtin_amdgcn_cvt_pk_fp8_f32(b.z, b.w, hi, true);
  out[i] = make_uint2((unsigned)lo, (unsigned)hi);
}

// ---- effective targets, ignore flags, divisor ----
__global__ void prep_targ(const int* __restrict__ targ, int* __restrict__ teff,
                          int* __restrict__ ign, float* __restrict__ divisor) {
  __shared__ int cnt[16];
  int local = 0;
  for (int i = threadIdx.x; i < N_TOK; i += 1024) {
    int t = targ[i];
    if (t != IGNIDX) local++;
    int pos = i & (N_TOK / 4 - 1);
    int te;
    if (pos < N_TOK / 4 - 1)      te = targ[i + 1];
    else if (i == N_TOK - 1)      te = IGNIDX;
    else                          te = targ[i + 2];
    ign[i] = (te == IGNIDX) ? 1 : 0;
    te = te < 0 ? 0 : (te > NCLS - 1 ? NCLS - 1 : te);
    teff[i] = te;
  }
#pragma unroll
  for (int d = 1; d < 64; d <<= 1) local += __shfl_xor(local, d);
  if ((threadIdx.x & 63) == 0) cnt[threadIdx.x >> 6] = local;
  __syncthreads();
  if (threadIdx.x == 0) {
    int t = 0;
    for (int i = 0; i < 16; i++) t += cnt[i];
    divisor[0] = (float)t;
  }
}

// LDS flat layout (bytes): A0 @0, A1 @32768, B0 @65536, B1 @98304.
// Staged 16B slot s of row r holds logical K-granule s ^ (r&7) (involution).

// direct global->LDS, 16B/lane, linear LDS dest (wave-uniform base)
#define STG(GSRC, LOFF) __builtin_amdgcn_global_load_lds(                  \
    (const __attribute__((address_space(1))) void*)(GSRC),                 \
    (__attribute__((address_space(3))) void*)&lds[LOFF], 16, 0, 0)

// one 16x16x128 fragment = 2 x ds_read_b128 (even/odd granule), 32-bit addrs.
// shufflevector concat (not element inserts) so the backend can place the two
// b128 results as adjacent register quads of the i32x8 without v_movs.
#define FRAG(DST, EB, OB, IMM)                                             \
  { i32x4 _a = *(const i32x4*)&lds[(EB) + (IMM)];                          \
    i32x4 _b = *(const i32x4*)&lds[(OB) + (IMM)];                          \
    DST = __builtin_shufflevector(_a, _b, 0, 1, 2, 3, 4, 5, 6, 7); }

#define LOADA(ARR, MH, EB, OB)                 \
  FRAG(ARR[0], EB, OB, (MH)*8192 + 0)          \
  FRAG(ARR[1], EB, OB, (MH)*8192 + 2048)       \
  FRAG(ARR[2], EB, OB, (MH)*8192 + 4096)       \
  FRAG(ARR[3], EB, OB, (MH)*8192 + 6144)

#define LOADB(DST, NH, EB, OB)                 \
  FRAG(DST[0], EB, OB, (NH)*4096 + 0)          \
  FRAG(DST[1], EB, OB, (NH)*4096 + 2048)

// 16 MFMA = one m-half x full n, operand set AF
#define DOMFMA2(MH, AF)                                                     \
  _Pragma("unroll")                                                         \
  for (int mm = 0; mm < 4; mm++) {                                          \
    _Pragma("unroll")                                                       \
    for (int nn = 0; nn < 2; nn++)                                          \
      acc[(MH)*4 + mm][nn] =                                                \
          __builtin_amdgcn_mfma_scale_f32_16x16x128_f8f6f4(                 \
              AF[mm], bF0[nn], acc[(MH)*4 + mm][nn],                        \
              0, 0, 0, SCALE_ONE, 0, SCALE_ONE);                            \
    _Pragma("unroll")                                                       \
    for (int nn = 0; nn < 2; nn++)                                          \
      acc[(MH)*4 + mm][2 + nn] =                                            \
          __builtin_amdgcn_mfma_scale_f32_16x16x128_f8f6f4(                 \
              AF[mm], bF1[nn], acc[(MH)*4 + mm][2 + nn],                    \
              0, 0, 0, SCALE_ONE, 0, SCALE_ONE);                            \
  }

// ---- fused 256x256 MX-fp8 GEMM + per-tile sum(exp) partials ----
// Round-14: r12 schedule (1 phase + 1 barrier + vmcnt(0) per K-tile,
// distance-1 full-tile prefetch into the other buffer), with the A-fragment
// register WAR removed: all 24 ds_reads issue up front into DISTINCT register
// sets (aF0/aF1), so the compiler's counted lgkm waits let the aF1 reads
// drain under the first 16-MFMA cluster instead of serializing after it.
__launch_bounds__(512, 2)
__global__ void gemm_lse(const u8* __restrict__ Xf8, const u8* __restrict__ Wf8,
                         const int* __restrict__ teff, float* __restrict__ gt,
                         float* __restrict__ partial) {
  __shared__ __align__(16) u8 lds[131072];

  const int tid = threadIdx.x;
  const int w = tid >> 6, l = tid & 63;
  const int wm = w >> 2, wn = w & 3;          // 2 x 4 wave grid
  const int hi = l >> 4, lo = l & 15;
  const int q = l & 7;

  // XCD-chunked bijective swizzle (2000 % 8 == 0)
  const int bid = blockIdx.x;
  const int wg = (bid & 7) * (NTM * NTN / 8) + (bid >> 3);
  const int bx = wg & (NTM - 1), by = wg >> 4;
  const int rowBase = bx * BM, colBase = by * BN;

  // uniform global bases (SGPR) + invariant per-lane 32-bit offsets
  const u8* pA = Xf8 + (size_t)rowBase * DIM;
  const u8* pB = Wf8 + (size_t)colBase * DIM;
  const int lr = l >> 3, lg = (l & 7) ^ lr;
  const int voffA = (w * 8 + lr) * DIM + lg * 16;
  const int voffB = ((w >> 2) * 64 + (w & 3) * 8 + lr) * DIM + lg * 16;
  // wave-uniform LDS staging bases
  const int ldsAb = w * 1024;
  const int ldsBb = 65536 + (w >> 2) * 8192 + (w & 3) * 1024;

  // per-lane fragment-read bases (32-bit LDS byte offsets)
  const int slotE = (((hi * 2) ^ q)) << 4;
  const int aE = (wm * 128 + lo) * BKB + slotE;
  const int aO = aE ^ 16;
  const int bE = 65536 + (wn * 64 + lo) * BKB + slotE;
  const int bO = bE ^ 16;

  f32x4 acc[8][4] = {};

  // ---- prologue: stage all of tile 0 -> buf0 (8 loads), full drain ----
  STG(pA + voffA, ldsAb);                  STG(pA + 131072 + voffA, ldsAb + 16384);
  STG(pA + 65536 + voffA, ldsAb + 8192);   STG(pA + 196608 + voffA, ldsAb + 24576);
  STG(pB + voffB, ldsBb);                  STG(pB + 131072 + voffB, ldsBb + 16384);
  STG(pB + 32768 + voffB, ldsBb + 4096);   STG(pB + 163840 + voffB, ldsBb + 20480);
  VMCNT0; FENCE; BAR;

  i32x8 aF0[4], aF1[4], bF0[2], bF1[2];

#pragma unroll 1
  for (int t = 0; t < KT; t++) {
    const int bs  = (t & 1) << 15;          // current buffer byte offset
    const int bn_ = bs ^ 32768;             // other buffer
    const int aEc = aE + bs, aOc = aO + bs;
    const int bEc = bE + bs, bOc = bO + bs;
    const int k1 = ((t + 1) & 7) * BKB;     // uniform (SALU)

    // stage tile t+1 (all 4 regions) -> other buffer; hides under MFMAs
    STG(pA + k1 + voffA, ldsAb + bn_);
    STG(pA + (k1 + 131072) + voffA, ldsAb + 16384 + bn_);
    STG(pA + (k1 + 65536) + voffA, ldsAb + 8192 + bn_);
    STG(pA + (k1 + 196608) + voffA, ldsAb + 24576 + bn_);
    STG(pB + k1 + voffB, ldsBb + bn_);
    STG(pB + (k1 + 131072) + voffB, ldsBb + 16384 + bn_);
    STG(pB + (k1 + 32768) + voffB, ldsBb + 4096 + bn_);
    STG(pB + (k1 + 163840) + voffB, ldsBb + 20480 + bn_);

    // ALL 24 reads up front, distinct register sets (no WAR) -> aF1 reads
    // drain under the first MFMA cluster via compiler's counted lgkm waits
    LOADA(aF0, 0, aEc, aOc)
    LOADB(bF0, 0, bEc, bOc)
    LOADB(bF1, 1, bEc, bOc)
    LOADA(aF1, 1, aEc, aOc)

    __builtin_amdgcn_s_setprio(1);
    DOMFMA2(0, aF0)
    DOMFMA2(1, aF1)
    __builtin_amdgcn_s_setprio(0);

    VMCNT0; FENCE; BAR;
  }

  // ---- epilogue: per-row sum(exp) over this 256-col tile + gt extraction ----
  float* red = (float*)lds;
#pragma unroll
  for (int m = 0; m < 8; m++) {
#pragma unroll
    for (int j = 0; j < 4; j++) {
      const int rloc = wm * 128 + m * 16 + hi * 4 + j;
      const int gr = rowBase + rloc;
      const int te = teff[gr];
      float s = 0.f;
#pragma unroll
      for (int n = 0; n < 4; n++) {
        float v = acc[m][n][j];
        const int gc = colBase + wn * 64 + n * 16 + lo;
        if (te == gc) gt[gr] = v;
        s += __expf(v);
      }
#pragma unroll
      for (int d = 1; d < 16; d <<= 1) s += __shfl_xor(s, d);
      if (lo == 0) red[wn * 256 + rloc] = s;
    }
  }
  __syncthreads();
  if (tid < 256) {
    float S = red[tid] + red[256 + tid] + red[512 + tid] + red[768 + tid];
    partial[(size_t)(rowBase + tid) * NTN + by] = S;
  }
}

// ---- combine 125 tile partials per row -> per-token loss ----
__global__ void reduce_lse(const float* __restrict__ partial, const float* __restrict__ gt,
                           const int* __restrict__ ign, const float* __restrict__ divisor,
                           float* __restrict__ pertok) {
  int r = blockIdx.x * 4 + (threadIdx.x >> 6);
  int l = threadIdx.x & 63;
  float S = 0.f;
  for (int p = l; p < NTN; p += 64) S += partial[(size_t)r * NTN + p];
#pragma unroll
  for (int d = 1; d < 64; d <<= 1) S += __shfl_xor(S, d);
  if (l == 0) {
    float lse = __logf(S);
    pertok[r] = ign[r] ? 0.f : (lse - gt[r]) / divisor[0];
  }
}

// ---- deterministic final sum ----
__global__ void final_sum(const float* __restrict__ pertok, float* __restrict__ out) {
  __shared__ float red[16];
  float s = 0.f;
  for (int i = threadIdx.x; i < N_TOK; i += 1024) s += pertok[i];
#pragma unroll
  for (int d = 1; d < 64; d <<= 1) s += __shfl_xor(s, d);
  if ((threadIdx.x & 63) == 0) red[threadIdx.x >> 6] = s;
  __syncthreads();
  if (threadIdx.x == 0) {
    float t = 0.f;
    for (int i = 0; i < 16; i++) t += red[i];
    out[0] = t;
  }
}

extern "C" void kernel_launch(void* const* d_in, const int* in_sizes, int n_in,
                              void* d_out, int out_size, void* d_ws, size_t ws_size,
                              hipStream_t stream) {
  const float* x = (const float*)d_in[0];       // [4096,1024] f32
  const float* w = (const float*)d_in[1];       // [32000,1024] f32
  const int* targ = (const int*)d_in[2];        // [4096] int
  float* out = (float*)d_out;

  char* ws = (char*)d_ws;
  u8*    Xf8     = (u8*)(ws);                      // 4,194,304 B
  u8*    Wf8     = (u8*)(ws + 4194304);            // 32,768,000 B
  float* partial = (float*)(ws + 36962304);        // 2,048,000 B
  float* gt      = (float*)(ws + 39010304);        // 16,384 B
  int*   teff    = (int*)(ws + 39026688);          // 16,384 B
  int*   ign     = (int*)(ws + 39043072);          // 16,384 B
  float* divisor = (float*)(ws + 39059456);        // 256 B
  float* pertok  = (float*)(ws + 39059712);        // 16,384 B

  {
    int n8 = N_TOK * DIM / 8;                      // 524288
    cvt_fp8<<<(n8 + 255) / 256, 256, 0, stream>>>((const float4*)x, (uint2*)Xf8, n8);
  }
  {
    int n8 = NCLS * DIM / 8;                       // 4,096,000
    cvt_fp8<<<(n8 + 255) / 256, 256, 0, stream>>>((const float4*)w, (uint2*)Wf8, n8);
  }
  prep_targ<<<1, 1024, 0, stream>>>(targ, teff, ign, divisor);

  gemm_lse<<<NTM * NTN, 512, 0, stream>>>(Xf8, Wf8, teff, gt, partial);  // 2000 blocks

  reduce_lse<<<N_TOK / 4, 256, 0, stream>>>(partial, gt, ign, divisor, pertok);
  final_sum<<<1, 1024, 0, stream>>>(pertok, out);
}